// Round 7
// baseline (101.898 us; speedup 1.0000x reference)
//
#include <hip/hip_runtime.h>
#include <hip/hip_fp16.h>
#include <math.h>

#define DET 512
#define NA 180
#define NTILES 1024                   // 32 x 32 tiles of 16x16 pixels
#define TANG_FLOATS (NTILES * NA * 4) // 2.95 MB
#define CHUNK 5                       // angles per staged chunk -> 1 gl_lds per wave per STAGE
#define WWIN 24
#define NCH 18                        // 18 chunks x 5 angles = 90 per half
#define NSLOT (CHUNK * WWIN * 2)      // 240 uint4 slots per chunk (covers both gg groups)
#define NBUF 4                        // 4-deep buffer ring per half, 3 chunks staged ahead
#define ZERO_IDX (NA * DET * 2)       // zero uint4 slot index in xsT2
#define PREPB 360                     // tang tail blocks (512 thr): 360*512 = 184320 = NTILES*NA

typedef _Float16 half2_t __attribute__((ext_vector_type(2)));

// direct global->LDS DMA, 16 B per lane; lds dest = wave-uniform base + lane*16
__device__ __forceinline__ void async_copy16(void* lds, const void* g) {
    __builtin_amdgcn_global_load_lds(
        (const __attribute__((address_space(1))) unsigned*)g,
        (__attribute__((address_space(3))) unsigned*)(unsigned)(unsigned long long)lds,
        16, 0, 0);
}

// ws layout (floats):
//  [0, TANG_FLOATS)  : tang float4 per (tile,angle): {bias=255.5-w0, C, S, w0 int bits}
//  then xsT2         : uint4[NA*DET*2] delta-packed sinogram (2.95 MB):
//                      uint4 (a,d,g) = { half2(s_b[d], s_b[d+1]-s_b[d]) : b = 4g..4g+3 }
//                      + one zero uint4 at ZERO_IDX (OOB staging target)

// ---------------- fused prep + filter ----------------
// FIR parity-skip (odd-tap table) + 512-thread blocks: 8 waves = 2 batches x 4 j-quarters.
// (no out-zeroing: backproj is single-writer again and stores every pixel)
__global__ __launch_bounds__(512) void prep_filter_kernel(const float* __restrict__ x,
                                                          float4* __restrict__ tang,
                                                          unsigned* __restrict__ xsT2) {
    const int t = threadIdx.x;
    if (blockIdx.x >= 4 * NA) {
        const int pb = blockIdx.x - 4 * NA;
        int idx = pb * 512 + t;
        if (idx < NTILES * NA) {
            int tile = idx / NA;
            int a = idx - tile * NA;
            float th = (float)a * 0.017453292519943295f;
            float C = 255.5f * cosf(th);
            float S = 255.5f * sinf(th);
            int x0 = (tile & 31) << 4, y0 = (tile >> 5) << 4;
            float xga = (float)(2 * x0 - 511)        * (1.0f / 511.0f);
            float xgb = (float)(2 * (x0 + 15) - 511) * (1.0f / 511.0f);
            float yga = (float)(2 * y0 - 511)        * (1.0f / 511.0f);
            float ygb = (float)(2 * (y0 + 15) - 511) * (1.0f / 511.0f);
            float mn = 255.5f + fminf(xga * C, xgb * C) + fminf(-yga * S, -ygb * S);
            int w0 = (int)floorf(mn) - 1;     // -1 slack for fma rounding differences
            tang[idx] = make_float4(255.5f - (float)w0, C, S, __int_as_float(w0));
        }
        if (pb == 0 && t == 0) {
            uint4* z = (uint4*)xsT2 + ZERO_IDX;
            *z = make_uint4(0u, 0u, 0u, 0u);
        }
        return;
    }

    // ---- filter: wave w -> local batch lb=w>>2 (global 2z+lb), j-quarter q=w&3 ----
    __shared__ float xcols[2][DET];               // 4 KB
    __shared__ __align__(16) float god_raw[520];  // odd-tap table + 4-slot front guard
    __shared__ float part[8][DET];                // 16 KB
    float* godp = god_raw + 4;                    // godp[m] = g[2m+1-512], m in [0,512)

    const int a = blockIdx.x >> 2;
    const int z = blockIdx.x & 3;

    for (int i = t; i < 520; i += 512) {
        int m = i - 4;
        float g = 0.0f;
        if (m >= 0) {
            float fk = (float)(2 * m + 1 - 512);          // odd, never 0
            g = -0.20264236728467558f / (fk * fk);        // -2/pi^2 / k^2
        }
        god_raw[i] = g;
    }
    for (int i = t; i < 2 * DET; i += 512) {
        int b = i >> 9, j = i & 511;
        xcols[b][j] = x[((2 * z + b) * DET + j) * NA + a];
    }
    __syncthreads();

    const int w  = t >> 6, l = t & 63;
    const int lb = w >> 2, q = w & 3;
    const int d0 = l << 3;
    const int jstart = q << 7;

    float acc[8];
#pragma unroll
    for (int r = 0; r < 8; ++r) acc[r] = 0.0f;

    // odd-tap window: Wod[4+i] = godp[b+i]; tap for (d=d0+r, j=j0+jj), r-jj odd:
    // godp[b + (7+r-jj)/2] where b = (504 + d0 - j0)/2
    int b = 252 + (d0 >> 1) - (q << 6);
    float Wod[12];
    *(float4*)(Wod)     = *(const float4*)(godp + b - 4);
    *(float4*)(Wod + 4) = *(const float4*)(godp + b);
    *(float4*)(Wod + 8) = *(const float4*)(godp + b + 4);
    float xv[8];
    *(float4*)(xv)     = *(const float4*)(&xcols[lb][jstart]);
    *(float4*)(xv + 4) = *(const float4*)(&xcols[lb][jstart + 4]);

    for (int j0 = jstart; j0 < jstart + 128; j0 += 8) {
        float nxv[8]; float4 nw;
        const bool more = (j0 < jstart + 120);
        if (more) {
            *(float4*)(nxv)     = *(const float4*)(&xcols[lb][j0 + 8]);
            *(float4*)(nxv + 4) = *(const float4*)(&xcols[lb][j0 + 12]);
            nw = *(const float4*)(godp + b - 8);   // window slides by 4 per step
        }
#pragma unroll
        for (int jj = 0; jj < 8; ++jj)
#pragma unroll
            for (int r = ((jj + 1) & 1); r < 8; r += 2)   // r-jj odd only (g even taps = 0)
                acc[r] = fmaf(xv[jj], Wod[4 + ((7 + r - jj) >> 1)], acc[r]);
        if (more) {
#pragma unroll
            for (int i = 7; i >= 0; --i) Wod[i + 4] = Wod[i];
            *(float4*)(Wod) = nw;
#pragma unroll
            for (int i = 0; i < 8; ++i) xv[i] = nxv[i];
            b -= 4;
        }
    }

    // k=0 tap: out[d] += 0.5*x[d], owned by the j-quarter containing j==d
    if ((d0 >> 7) == q) {
        float xd[8];
        *(float4*)(xd)     = *(const float4*)(&xcols[lb][d0]);
        *(float4*)(xd + 4) = *(const float4*)(&xcols[lb][d0 + 4]);
#pragma unroll
        for (int r = 0; r < 8; ++r) acc[r] = fmaf(0.5f, xd[r], acc[r]);
    }

    *(float4*)(&part[w][d0])     = *(const float4*)(acc);
    *(float4*)(&part[w][d0 + 4]) = *(const float4*)(acc + 4);
    __syncthreads();

    // reduce j-quarters + delta pack: word = half2(v0, v1-v0); d=511 pairs with v1=0
    for (int i = t; i < DET; i += 512) {
        unsigned pw[2];
#pragma unroll
        for (int bq = 0; bq < 2; ++bq) {
            float v0 = (part[4 * bq][i]     + part[4 * bq + 1][i])
                     + (part[4 * bq + 2][i] + part[4 * bq + 3][i]);
            float v1 = 0.0f;
            if (i < DET - 1)
                v1 = (part[4 * bq][i + 1]     + part[4 * bq + 1][i + 1])
                   + (part[4 * bq + 2][i + 1] + part[4 * bq + 3][i + 1]);
            __half2 hh = __halves2half2(__float2half_rn(v0), __float2half_rn(v1 - v0));
            pw[bq] = *(unsigned*)&hh;
        }
        *(uint2*)(xsT2 + ((size_t)a * DET + i) * 8 + 4 * (z >> 1) + 2 * (z & 1)) =
            make_uint2(pw[0], pw[1]);
    }
}

// ---------------- backprojection: single-writer 512-thr, counted-vmcnt ring per half ----------------
// grid 1024: one block per tile. Waves 0-3 (hh=0) -> angles [0,90), waves 4-7 (hh=1) -> [90,180).
// Each half runs the R3-proven pipeline: CHUNK=5, NBUF=4 ring, 3 chunks in flight,
// s_waitcnt vmcnt(2) (never 0 until drain). 18 shared barriers; vmcnt exact per wave
// (every wave issues exactly 1 gl_lds per STAGE). Epilogue: half-1 partials -> LDS,
// half-0 adds + plain masked stores. No atomics, no out pre-zero. 32 waves/CU.
__global__ __launch_bounds__(512, 4) void backproj_kernel(const float4* __restrict__ tang,
                                                          const uint4* __restrict__ xs,
                                                          float* __restrict__ out) {
    __shared__ uint4 win[2][NBUF][NSLOT];   // [half][buf][slot] = 30.72 KB
    __shared__ int   wtab[NA];              // per-angle w0, both halves

    const int tile = blockIdx.x;
    const int x0 = (tile & 31) << 4, y0 = (tile >> 5) << 4;
    const int t = threadIdx.x;
    const int hh = t >> 8;            // angle half (wave-uniform)
    const int tl = t & 255;           // pixel id within tile
    const int abase = hh * 90;
    const int px = tl & 15, py = tl >> 4;
    const float xg = (float)(2 * (x0 + px) - 511) * (1.0f / 511.0f);
    const float yg = (float)(2 * (y0 + py) - 511) * (1.0f / 511.0f);

    float acc[8];
#pragma unroll
    for (int j = 0; j < 8; ++j) acc[j] = 0.0f;

    const float4* ta = tang + (size_t)tile * NA;
    const uint4*  zs = xs + ZERO_IDX;

    // per-thread slot decomposition (fixed across stages): slot tl -> (gg, ci, off)
    const int gg_pre  = (tl >= CHUNK * WWIN) ? 1 : 0;
    const int r_pre   = tl - gg_pre * (CHUNK * WWIN);
    const int ci_pre  = r_pre / WWIN;
    const int off_pre = r_pre - ci_pre * WWIN;

    // fill w0 table (one global gather, drained by the syncthreads below)
    if (t < NA) wtab[t] = __float_as_int(ta[t].w);
    __syncthreads();

    // STAGE(cc): one gl_lds per wave into this half's ring buffer cc&3; no other VMEM
#define STAGE(CC)                                                              \
    {                                                                          \
        int cc = (CC);                                                         \
        if (tl < NSLOT) {                                                      \
            int a = cc * CHUNK + ci_pre;                                       \
            int d = wtab[abase + a] + off_pre;                                 \
            const uint4* src = ((unsigned)d < 512u)                            \
                ? &xs[((size_t)(abase + a) * DET + d) * 2 + gg_pre] : zs;      \
            async_copy16(&win[hh][cc & 3][tl & 192], src);                     \
        }                                                                      \
    }

    STAGE(0); STAGE(1); STAGE(2);   // 3 chunks in flight per half (vmcnt=3 per wave)

    for (int c = 0; c < NCH; ++c) {
        // retire chunk c only; chunks c+1, c+2 stay in flight across the barrier
        if (c < NCH - 2)       asm volatile("s_waitcnt vmcnt(2)" ::: "memory");
        else if (c == NCH - 2) asm volatile("s_waitcnt vmcnt(1)" ::: "memory");
        else                   asm volatile("s_waitcnt vmcnt(0)" ::: "memory");
        __builtin_amdgcn_s_barrier();
        __builtin_amdgcn_sched_barrier(0);

        if (c + 3 < NCH) STAGE(c + 3);   // ring slot (c+3)&3 freed by compute(c-1) pre-barrier

        const uint4* base = &win[hh][c & 3][0];
#pragma unroll
        for (int ci = 0; ci < CHUNK; ++ci) {
            float4 A = ta[abase + c * CHUNK + ci];     // uniform -> s_load_dwordx4 (lgkmcnt)
            float yv = fmaf(xg, A.y, A.x) - yg * A.z;  // window-relative, >= 1
            float fi = floorf(yv);
            int  off = (int)fi;
            float wgt = yv - fi;
            auto pkw = __builtin_amdgcn_cvt_pkrtz(1.0f, wgt);   // (1, w) weights
            half2_t wv = *(half2_t*)&pkw;
            uint4 u0 = base[ci * WWIN + off];                  // ds_read_b128
            uint4 u1 = base[CHUNK * WWIN + ci * WWIN + off];   // ds_read_b128, +1920B imm
            acc[0] = __builtin_amdgcn_fdot2(*(half2_t*)&u0.x, wv, acc[0], false);
            acc[1] = __builtin_amdgcn_fdot2(*(half2_t*)&u0.y, wv, acc[1], false);
            acc[2] = __builtin_amdgcn_fdot2(*(half2_t*)&u0.z, wv, acc[2], false);
            acc[3] = __builtin_amdgcn_fdot2(*(half2_t*)&u0.w, wv, acc[3], false);
            acc[4] = __builtin_amdgcn_fdot2(*(half2_t*)&u1.x, wv, acc[4], false);
            acc[5] = __builtin_amdgcn_fdot2(*(half2_t*)&u1.y, wv, acc[5], false);
            acc[6] = __builtin_amdgcn_fdot2(*(half2_t*)&u1.z, wv, acc[6], false);
            acc[7] = __builtin_amdgcn_fdot2(*(half2_t*)&u1.w, wv, acc[7], false);
        }
    }

    // combine halves through LDS (all DMA retired by the c=NCH-1 vmcnt(0);
    // this barrier also ensures every thread's last ds_reads are consumed)
    __syncthreads();
    float* red = (float*)&win[0][0][0];   // 8 KB overlay, red[j*256 + tl] (conflict-free)
    if (hh == 1) {
#pragma unroll
        for (int j = 0; j < 8; ++j) red[j * 256 + tl] = acc[j];
    }
    __syncthreads();
    if (hh == 0) {
        const float r2 = xg * xg + yg * yg;
        const float m  = (r2 <= 1.0f) ? 0.008726646259971648f : 0.0f;  // pi/360 masked
        const size_t pbase = ((size_t)(y0 + py) << 9) + (size_t)(x0 + px);
#pragma unroll
        for (int j = 0; j < 8; ++j)
            out[((size_t)j << 18) + pbase] = (acc[j] + red[j * 256 + tl]) * m;
    }
}

extern "C" void kernel_launch(void* const* d_in, const int* in_sizes, int n_in,
                              void* d_out, int out_size, void* d_ws, size_t ws_size,
                              hipStream_t stream) {
    const float* x = (const float*)d_in[0];
    float* out = (float*)d_out;
    float* ws  = (float*)d_ws;

    float4*   tang = (float4*)ws;
    unsigned* xsT2 = (unsigned*)(ws + TANG_FLOATS);

    prep_filter_kernel<<<4 * NA + PREPB, 512, 0, stream>>>(x, tang, xsT2);
    backproj_kernel<<<NTILES, 512, 0, stream>>>(tang, (const uint4*)xsT2, out);
}

// Round 8
// 93.532 us; speedup vs baseline: 1.0895x; 1.0895x over previous
//
#include <hip/hip_runtime.h>
#include <hip/hip_fp16.h>
#include <math.h>

#define DET 512
#define NA 180
#define NTILES 1024                   // 32 x 32 tiles of 16x16 pixels
#define TANG_FLOATS (NTILES * NA * 4) // 2.95 MB
#define CHUNK 5                       // angles per staged chunk -> 1 gl_lds per wave per STAGE
#define WWIN 24
#define NCH 18                        // 18 chunks x 5 angles = 90 per half-block
#define NSLOT (CHUNK * WWIN * 2)      // 240 uint4 slots per chunk (covers both gg groups)
#define NBUF 4                        // 4-deep buffer ring, 3 chunks staged ahead
#define ZERO_IDX (NA * DET * 2)       // zero uint4 slot index in xsT2
#define PREPB 360                     // tang/zero tail blocks (512 thr): 360*512 = 184320

typedef _Float16 half2_t __attribute__((ext_vector_type(2)));

// direct global->LDS DMA, 16 B per lane; lds dest = wave-uniform base + lane*16
__device__ __forceinline__ void async_copy16(void* lds, const void* g) {
    __builtin_amdgcn_global_load_lds(
        (const __attribute__((address_space(1))) unsigned*)g,
        (__attribute__((address_space(3))) unsigned*)(unsigned)(unsigned long long)lds,
        16, 0, 0);
}

// ws layout (floats):
//  [0, TANG_FLOATS)  : tang float4 per (tile,angle): {bias=255.5-w0, C, S, w0 int bits}
//  then xsT2         : uint4[NA*DET*2] delta-packed sinogram (2.95 MB):
//                      uint4 (a,d,g) = { half2(s_b[d], s_b[d+1]-s_b[d]) : b = 4g..4g+3 }
//                      + one zero uint4 at ZERO_IDX (OOB staging target)

// ---------------- fused prep + filter + out-zero (R6 proven) ----------------
// FIR parity-skip (odd-tap table) + 512-thread blocks: 8 waves = 2 batches x 4 j-quarters.
__global__ __launch_bounds__(512) void prep_filter_kernel(const float* __restrict__ x,
                                                          float4* __restrict__ tang,
                                                          unsigned* __restrict__ xsT2,
                                                          float4* __restrict__ out4) {
    const int t = threadIdx.x;
    if (blockIdx.x >= 4 * NA) {
        const int pb = blockIdx.x - 4 * NA;
        int idx = pb * 512 + t;
        if (idx < NTILES * NA) {
            int tile = idx / NA;
            int a = idx - tile * NA;
            float th = (float)a * 0.017453292519943295f;
            float C = 255.5f * cosf(th);
            float S = 255.5f * sinf(th);
            int x0 = (tile & 31) << 4, y0 = (tile >> 5) << 4;
            float xga = (float)(2 * x0 - 511)        * (1.0f / 511.0f);
            float xgb = (float)(2 * (x0 + 15) - 511) * (1.0f / 511.0f);
            float yga = (float)(2 * y0 - 511)        * (1.0f / 511.0f);
            float ygb = (float)(2 * (y0 + 15) - 511) * (1.0f / 511.0f);
            float mn = 255.5f + fminf(xga * C, xgb * C) + fminf(-yga * S, -ygb * S);
            int w0 = (int)floorf(mn) - 1;     // -1 slack for fma rounding differences
            tang[idx] = make_float4(255.5f - (float)w0, C, S, __int_as_float(w0));
        }
        if (pb == 0 && t == 0) {
            uint4* z = (uint4*)xsT2 + ZERO_IDX;
            *z = make_uint4(0u, 0u, 0u, 0u);
        }
        // zero d_out: 524288 float4 spread over 360 blocks (atomic epilogue needs it)
        for (int q = t; q < 1457; q += 512) {
            int o = pb * 1457 + q;
            if (o < (1 << 19))
                out4[o] = make_float4(0.0f, 0.0f, 0.0f, 0.0f);
        }
        return;
    }

    // ---- filter: wave w -> local batch lb=w>>2 (global 2z+lb), j-quarter q=w&3 ----
    __shared__ float xcols[2][DET];               // 4 KB
    __shared__ __align__(16) float god_raw[520];  // odd-tap table + 4-slot front guard
    __shared__ float part[8][DET];                // 16 KB
    float* godp = god_raw + 4;                    // godp[m] = g[2m+1-512], m in [0,512)

    const int a = blockIdx.x >> 2;
    const int z = blockIdx.x & 3;

    for (int i = t; i < 520; i += 512) {
        int m = i - 4;
        float g = 0.0f;
        if (m >= 0) {
            float fk = (float)(2 * m + 1 - 512);          // odd, never 0
            g = -0.20264236728467558f / (fk * fk);        // -2/pi^2 / k^2
        }
        god_raw[i] = g;
    }
    for (int i = t; i < 2 * DET; i += 512) {
        int b = i >> 9, j = i & 511;
        xcols[b][j] = x[((2 * z + b) * DET + j) * NA + a];
    }
    __syncthreads();

    const int w  = t >> 6, l = t & 63;
    const int lb = w >> 2, q = w & 3;
    const int d0 = l << 3;
    const int jstart = q << 7;

    float acc[8];
#pragma unroll
    for (int r = 0; r < 8; ++r) acc[r] = 0.0f;

    // odd-tap window: Wod[4+i] = godp[b+i]; tap for (d=d0+r, j=j0+jj), r-jj odd:
    // godp[b + (7+r-jj)/2] where b = (504 + d0 - j0)/2
    int b = 252 + (d0 >> 1) - (q << 6);
    float Wod[12];
    *(float4*)(Wod)     = *(const float4*)(godp + b - 4);
    *(float4*)(Wod + 4) = *(const float4*)(godp + b);
    *(float4*)(Wod + 8) = *(const float4*)(godp + b + 4);
    float xv[8];
    *(float4*)(xv)     = *(const float4*)(&xcols[lb][jstart]);
    *(float4*)(xv + 4) = *(const float4*)(&xcols[lb][jstart + 4]);

    for (int j0 = jstart; j0 < jstart + 128; j0 += 8) {
        float nxv[8]; float4 nw;
        const bool more = (j0 < jstart + 120);
        if (more) {
            *(float4*)(nxv)     = *(const float4*)(&xcols[lb][j0 + 8]);
            *(float4*)(nxv + 4) = *(const float4*)(&xcols[lb][j0 + 12]);
            nw = *(const float4*)(godp + b - 8);   // window slides by 4 per step
        }
#pragma unroll
        for (int jj = 0; jj < 8; ++jj)
#pragma unroll
            for (int r = ((jj + 1) & 1); r < 8; r += 2)   // r-jj odd only (g even taps = 0)
                acc[r] = fmaf(xv[jj], Wod[4 + ((7 + r - jj) >> 1)], acc[r]);
        if (more) {
#pragma unroll
            for (int i = 7; i >= 0; --i) Wod[i + 4] = Wod[i];
            *(float4*)(Wod) = nw;
#pragma unroll
            for (int i = 0; i < 8; ++i) xv[i] = nxv[i];
            b -= 4;
        }
    }

    // k=0 tap: out[d] += 0.5*x[d], owned by the j-quarter containing j==d
    if ((d0 >> 7) == q) {
        float xd[8];
        *(float4*)(xd)     = *(const float4*)(&xcols[lb][d0]);
        *(float4*)(xd + 4) = *(const float4*)(&xcols[lb][d0 + 4]);
#pragma unroll
        for (int r = 0; r < 8; ++r) acc[r] = fmaf(0.5f, xd[r], acc[r]);
    }

    *(float4*)(&part[w][d0])     = *(const float4*)(acc);
    *(float4*)(&part[w][d0 + 4]) = *(const float4*)(acc + 4);
    __syncthreads();

    // reduce j-quarters + delta pack: word = half2(v0, v1-v0); d=511 pairs with v1=0
    for (int i = t; i < DET; i += 512) {
        unsigned pw[2];
#pragma unroll
        for (int bq = 0; bq < 2; ++bq) {
            float v0 = (part[4 * bq][i]     + part[4 * bq + 1][i])
                     + (part[4 * bq + 2][i] + part[4 * bq + 3][i]);
            float v1 = 0.0f;
            if (i < DET - 1)
                v1 = (part[4 * bq][i + 1]     + part[4 * bq + 1][i + 1])
                   + (part[4 * bq + 2][i + 1] + part[4 * bq + 3][i + 1]);
            __half2 hh = __halves2half2(__float2half_rn(v0), __float2half_rn(v1 - v0));
            pw[bq] = *(unsigned*)&hh;
        }
        *(uint2*)(xsT2 + ((size_t)a * DET + i) * 8 + 4 * (z >> 1) + 2 * (z & 1)) =
            make_uint2(pw[0], pw[1]);
    }
}

// ---------------- backprojection: counted-vmcnt 4-buffer pipeline (R3/R6 proven) ----------------
// grid 2048: tile = bx & 1023, half = bx >> 10 (angles [90h, 90h+90)).
// CHUNK=5 -> each STAGE is exactly ONE global_load_lds per wave; per-block w0[] table in
// LDS means the main loop's ONLY vmcnt traffic is the gl_lds ring -> s_waitcnt vmcnt(2)
// (never 0) keeps 2 chunks of DMA in flight across every barrier (T3/T4 pattern).
// NEW (T5): s_setprio(1) around the fdot2 cluster — compute waves win SIMD arbitration
// over STAGE-issuing waves (phase-split regime where T5 is mechanism-applicable).
__global__ __launch_bounds__(256, 8) void backproj_kernel(const float4* __restrict__ tang,
                                                          const uint4* __restrict__ xs,
                                                          float* __restrict__ out) {
    __shared__ uint4 win[NBUF][NSLOT];   // 15.36 KB
    __shared__ int   wtab[90];           // per-angle w0 for this half

    const int tile = blockIdx.x & 1023;
    const int abase = (blockIdx.x >> 10) * 90;
    const int x0 = (tile & 31) << 4, y0 = (tile >> 5) << 4;
    const int t = threadIdx.x;
    const int px = t & 15, py = t >> 4;
    const float xg = (float)(2 * (x0 + px) - 511) * (1.0f / 511.0f);
    const float yg = (float)(2 * (y0 + py) - 511) * (1.0f / 511.0f);

    float acc[8];
#pragma unroll
    for (int j = 0; j < 8; ++j) acc[j] = 0.0f;

    const float4* ta = tang + (size_t)tile * NA;
    const uint4*  zs = xs + ZERO_IDX;

    // per-thread slot decomposition (fixed across stages): slot t -> (gg, ci, off)
    const int gg_pre  = (t >= CHUNK * WWIN) ? 1 : 0;
    const int r_pre   = t - gg_pre * (CHUNK * WWIN);
    const int ci_pre  = r_pre / WWIN;
    const int off_pre = r_pre - ci_pre * WWIN;

    // fill w0 table (one global gather, drained by the syncthreads below)
    if (t < 90) wtab[t] = __float_as_int(ta[abase + t].w);
    __syncthreads();

    // STAGE(cc): one gl_lds per wave into ring buffer cc&3; no other VMEM inside
#define STAGE(CC)                                                              \
    {                                                                          \
        int cc = (CC);                                                         \
        if (t < NSLOT) {                                                       \
            int a = cc * CHUNK + ci_pre;                                       \
            int d = wtab[a] + off_pre;                                         \
            const uint4* src = ((unsigned)d < 512u)                            \
                ? &xs[((size_t)(abase + a) * DET + d) * 2 + gg_pre] : zs;      \
            async_copy16(&win[cc & 3][t & 192], src);                          \
        }                                                                      \
    }

    STAGE(0); STAGE(1); STAGE(2);   // 3 chunks in flight (vmcnt=3 per wave)

    for (int c = 0; c < NCH; ++c) {
        // retire chunk c only; chunks c+1, c+2 stay in flight across the barrier
        if (c < NCH - 2)       asm volatile("s_waitcnt vmcnt(2)" ::: "memory");
        else if (c == NCH - 2) asm volatile("s_waitcnt vmcnt(1)" ::: "memory");
        else                   asm volatile("s_waitcnt vmcnt(0)" ::: "memory");
        __builtin_amdgcn_s_barrier();
        __builtin_amdgcn_sched_barrier(0);

        if (c + 3 < NCH) STAGE(c + 3);   // ring slot (c+3)&3 freed by compute(c-1) pre-barrier

        const uint4* base = &win[c & 3][0];
        __builtin_amdgcn_s_setprio(1);   // T5: favor compute waves over STAGE-issuing waves
#pragma unroll
        for (int ci = 0; ci < CHUNK; ++ci) {
            float4 A = ta[abase + c * CHUNK + ci];     // uniform -> s_load_dwordx4 (lgkmcnt)
            float yv = fmaf(xg, A.y, A.x) - yg * A.z;  // window-relative, >= 1
            float fi = floorf(yv);
            int  off = (int)fi;
            float wgt = yv - fi;
            auto pkw = __builtin_amdgcn_cvt_pkrtz(1.0f, wgt);   // (1, w) weights
            half2_t wv = *(half2_t*)&pkw;
            uint4 u0 = base[ci * WWIN + off];                  // ds_read_b128
            uint4 u1 = base[CHUNK * WWIN + ci * WWIN + off];   // ds_read_b128, +1920B imm
            acc[0] = __builtin_amdgcn_fdot2(*(half2_t*)&u0.x, wv, acc[0], false);
            acc[1] = __builtin_amdgcn_fdot2(*(half2_t*)&u0.y, wv, acc[1], false);
            acc[2] = __builtin_amdgcn_fdot2(*(half2_t*)&u0.z, wv, acc[2], false);
            acc[3] = __builtin_amdgcn_fdot2(*(half2_t*)&u0.w, wv, acc[3], false);
            acc[4] = __builtin_amdgcn_fdot2(*(half2_t*)&u1.x, wv, acc[4], false);
            acc[5] = __builtin_amdgcn_fdot2(*(half2_t*)&u1.y, wv, acc[5], false);
            acc[6] = __builtin_amdgcn_fdot2(*(half2_t*)&u1.z, wv, acc[6], false);
            acc[7] = __builtin_amdgcn_fdot2(*(half2_t*)&u1.w, wv, acc[7], false);
        }
        __builtin_amdgcn_s_setprio(0);
    }

    // two halves per address, fp32 add commutative -> deterministic
    const float r2 = xg * xg + yg * yg;
    const float m  = (r2 <= 1.0f) ? 0.008726646259971648f : 0.0f;  // pi/360 masked
    const size_t pbase = ((size_t)(y0 + py) << 9) + (size_t)(x0 + px);
#pragma unroll
    for (int j = 0; j < 8; ++j)
        atomicAdd(&out[((size_t)j << 18) + pbase], acc[j] * m);
}

extern "C" void kernel_launch(void* const* d_in, const int* in_sizes, int n_in,
                              void* d_out, int out_size, void* d_ws, size_t ws_size,
                              hipStream_t stream) {
    const float* x = (const float*)d_in[0];
    float* out = (float*)d_out;
    float* ws  = (float*)d_ws;

    float4*   tang = (float4*)ws;
    unsigned* xsT2 = (unsigned*)(ws + TANG_FLOATS);

    prep_filter_kernel<<<4 * NA + PREPB, 512, 0, stream>>>(x, tang, xsT2, (float4*)out);
    backproj_kernel<<<2 * NTILES, 256, 0, stream>>>(tang, (const uint4*)xsT2, out);
}